// Round 4
// baseline (1018.457 us; speedup 1.0000x reference)
//
#include <hip/hip_runtime.h>

// B=16, N=8192, C1=64, C2=128, C3=256, NP=32
// Bit-replication of a numpy fp32 reference: sequential accumulation,
// ascending contraction index, NO FMA (explicit __fmul_rn/__fadd_rn),
// correctly-rounded sqrt/div, top-k ties -> lower index.

__device__ __forceinline__ float bf16rne(float x) {
    unsigned u = __float_as_uint(x);
    u = (u + 0x7FFFu + ((u >> 16) & 1u)) & 0xFFFF0000u;
    return __uint_as_float(u);
}

// ---------------- per-channel scales: s = g / sqrt(v + 1e-5f), exact fp32 ----------------
__global__ void scales_kernel(const float* __restrict__ g1, const float* __restrict__ v1,
                              const float* __restrict__ g2, const float* __restrict__ v2,
                              const float* __restrict__ g3, const float* __restrict__ v3,
                              float* __restrict__ s) {
    int t = threadIdx.x;
    if (t < 64)       s[t] = __fdiv_rn(g1[t],       __fsqrt_rn(__fadd_rn(v1[t],       1e-5f)));
    else if (t < 192) s[t] = __fdiv_rn(g2[t - 64],  __fsqrt_rn(__fadd_rn(v2[t - 64],  1e-5f)));
    else if (t < 448) s[t] = __fdiv_rn(g3[t - 192], __fsqrt_rn(__fadd_rn(v3[t - 192], 1e-5f)));
}

// ---------------- fused MLP, numpy-exact fp32: x[16,3,8192] -> h[16,256,8192] ----------------
__global__ __launch_bounds__(128) void mlp_kernel(
        const float* __restrict__ x,
        const float* __restrict__ w1, const float* __restrict__ b1,
        const float* __restrict__ m1, const float* __restrict__ be1,
        const float* __restrict__ w2, const float* __restrict__ b2,
        const float* __restrict__ m2, const float* __restrict__ be2,
        const float* __restrict__ w3, const float* __restrict__ b3,
        const float* __restrict__ m3, const float* __restrict__ be3,
        const float* __restrict__ sc,
        float* __restrict__ h) {
    __shared__ float h2s[128][129];

    const float* s1 = sc;
    const float* s2 = sc + 64;
    const float* s3 = sc + 192;

    int t  = threadIdx.x;
    int pt = blockIdx.x * 128 + t;
    int b  = pt >> 13;
    int n  = pt & 8191;

    const float* xb = x + (size_t)b * 24576 + n;
    float x0 = xb[0], x1 = xb[8192], x2 = xb[16384];

    // layer 1: 3 -> 64  (acc = ((w0*x0 + w1*x1) + w2*x2), no FMA)
    float h1[64];
#pragma unroll
    for (int o = 0; o < 64; ++o) {
        float acc = __fmul_rn(w1[o * 3 + 0], x0);
        acc = __fadd_rn(acc, __fmul_rn(w1[o * 3 + 1], x1));
        acc = __fadd_rn(acc, __fmul_rn(w1[o * 3 + 2], x2));
        float hpb = __fadd_rn(acc, b1[o]);
        float tt  = __fsub_rn(hpb, m1[o]);
        float r   = __fadd_rn(__fmul_rn(tt, s1[o]), be1[o]);
        h1[o] = fmaxf(r, 0.0f);
    }

    // layer 2: 64 -> 128, sequential i ascending per channel, 4-channel ILP
    for (int o4 = 0; o4 < 128; o4 += 4) {
        float a0 = 0.f, a1 = 0.f, a2 = 0.f, a3 = 0.f;
        const float* wr0 = w2 + (o4 + 0) * 64;
        const float* wr1 = w2 + (o4 + 1) * 64;
        const float* wr2 = w2 + (o4 + 2) * 64;
        const float* wr3 = w2 + (o4 + 3) * 64;
#pragma unroll
        for (int ci = 0; ci < 64; ++ci) {
            float hv = h1[ci];
            a0 = __fadd_rn(a0, __fmul_rn(wr0[ci], hv));
            a1 = __fadd_rn(a1, __fmul_rn(wr1[ci], hv));
            a2 = __fadd_rn(a2, __fmul_rn(wr2[ci], hv));
            a3 = __fadd_rn(a3, __fmul_rn(wr3[ci], hv));
        }
#pragma unroll
        for (int j = 0; j < 4; ++j) {
            float aj = (j == 0) ? a0 : (j == 1) ? a1 : (j == 2) ? a2 : a3;
            int o = o4 + j;
            float hpb = __fadd_rn(aj, b2[o]);
            float tt  = __fsub_rn(hpb, m2[o]);
            float r   = __fadd_rn(__fmul_rn(tt, s2[o]), be2[o]);
            h2s[t][o] = fmaxf(r, 0.0f);
        }
    }

    // layer 3: 128 -> 256, no relu
    float* hb = h + (size_t)b * 2097152 + n;
    for (int o8 = 0; o8 < 256; o8 += 8) {
        float acc[8];
#pragma unroll
        for (int j = 0; j < 8; ++j) acc[j] = 0.f;
#pragma unroll 4
        for (int ci = 0; ci < 128; ++ci) {
            float hv = h2s[t][ci];
#pragma unroll
            for (int j = 0; j < 8; ++j)
                acc[j] = __fadd_rn(acc[j], __fmul_rn(w3[(o8 + j) * 128 + ci], hv));
        }
#pragma unroll
        for (int j = 0; j < 8; ++j) {
            int o = o8 + j;
            float hpb = __fadd_rn(acc[j], b3[o]);
            float tt  = __fsub_rn(hpb, m3[o]);
            float r   = __fadd_rn(__fmul_rn(tt, s3[o]), be3[o]);
            hb[(size_t)o * 8192] = r;
        }
    }
}

// ---------------- top-32 per row, fp32 keys, ties -> lower index ----------------
__global__ __launch_bounds__(256) void topk_kernel(const float* __restrict__ h,
                                                   int* __restrict__ idx_out) {
    __shared__ unsigned long long keys[8192];
    __shared__ unsigned long long wmax[4];

    int row = blockIdx.x;
    const float* hr = h + (size_t)row * 8192;
    int t = threadIdx.x;

    for (int i = t; i < 8192; i += 256) {
        unsigned u = __float_as_uint(hr[i]);
        u = (u & 0x80000000u) ? ~u : (u | 0x80000000u);   // monotonic map
        keys[i] = ((unsigned long long)u << 13) | (unsigned)(8191 - i);
    }
    __syncthreads();

    for (int pass = 0; pass < 32; ++pass) {
        unsigned long long m = 0ull;
#pragma unroll
        for (int j = 0; j < 32; ++j) {
            unsigned long long k = keys[t + j * 256];
            m = (k > m) ? k : m;
        }
#pragma unroll
        for (int s = 1; s < 64; s <<= 1) {
            unsigned long long o = __shfl_xor(m, s, 64);
            m = (o > m) ? o : m;
        }
        if ((t & 63) == 0) wmax[t >> 6] = m;
        __syncthreads();
        if (t == 0) {
            unsigned long long g = wmax[0];
            g = (wmax[1] > g) ? wmax[1] : g;
            g = (wmax[2] > g) ? wmax[2] : g;
            g = (wmax[3] > g) ? wmax[3] : g;
            int i = 8191 - (int)(g & 8191ull);
            idx_out[row * 32 + pass] = i;
            keys[i] = 0ull;
        }
        __syncthreads();
    }
}

// ---------------- gather: out[b,cf,k,cs] = bf16rne(h[b,cf,idx[b,cs,k]]) ----------------
__global__ __launch_bounds__(256) void gather_kernel(const float* __restrict__ h,
                                                     const int* __restrict__ idx,
                                                     float* __restrict__ out) {
    int id = blockIdx.x;
    int q  = id & 3;
    int k  = (id >> 2) & 31;
    int b  = id >> 7;
    int cs = threadIdx.x;

    int i = idx[(b * 256 + cs) * 32 + k];
    const float* hb = h + (size_t)b * 2097152;
    float* ob = out + (size_t)b * 2097152 + (size_t)k * 256 + cs;

#pragma unroll 4
    for (int cf = q * 64; cf < q * 64 + 64; ++cf) {
        ob[(size_t)cf * 8192] = bf16rne(hb[(size_t)cf * 8192 + i]);
    }
}

extern "C" void kernel_launch(void* const* d_in, const int* in_sizes, int n_in,
                              void* d_out, int out_size, void* d_ws, size_t ws_size,
                              hipStream_t stream) {
    const float* x   = (const float*)d_in[0];
    const float* w1  = (const float*)d_in[1];
    const float* b1  = (const float*)d_in[2];
    const float* g1  = (const float*)d_in[3];
    const float* be1 = (const float*)d_in[4];
    const float* m1  = (const float*)d_in[5];
    const float* v1  = (const float*)d_in[6];
    const float* w2  = (const float*)d_in[7];
    const float* b2  = (const float*)d_in[8];
    const float* g2  = (const float*)d_in[9];
    const float* be2 = (const float*)d_in[10];
    const float* m2  = (const float*)d_in[11];
    const float* v2  = (const float*)d_in[12];
    const float* w3  = (const float*)d_in[13];
    const float* b3  = (const float*)d_in[14];
    const float* g3  = (const float*)d_in[15];
    const float* be3 = (const float*)d_in[16];
    const float* m3  = (const float*)d_in[17];
    const float* v3  = (const float*)d_in[18];

    char* ws = (char*)d_ws;
    float* h    = (float*)(ws);                  // 134,217,728 B
    int*   idxb = (int*)(ws + 134217728);        //     524,288 B
    float* sc   = (float*)(ws + 134742016);      //       1,792 B

    scales_kernel<<<1, 448, 0, stream>>>(g1, v1, g2, v2, g3, v3, sc);
    mlp_kernel<<<1024, 128, 0, stream>>>(x, w1, b1, m1, be1,
                                         w2, b2, m2, be2,
                                         w3, b3, m3, be3, sc, h);
    topk_kernel<<<4096, 256, 0, stream>>>(h, idxb);
    gather_kernel<<<2048, 256, 0, stream>>>(h, idxb, (float*)d_out);
}